// Round 7
// baseline (250.835 us; speedup 1.0000x reference)
//
#include <hip/hip_runtime.h>
#include <hip/hip_bf16.h>

typedef __attribute__((ext_vector_type(8))) short short8;
typedef __attribute__((ext_vector_type(4))) short short4x;
typedef __attribute__((ext_vector_type(4))) float floatx4;

__device__ __forceinline__ short f2bf(float f) {
    unsigned u = __float_as_uint(f);
    u = u + 0x7fffu + ((u >> 16) & 1u);
    return (short)(u >> 16);
}
// truncating convert (values >=0, used for P only)
__device__ __forceinline__ short f2bf_rz(float f) {
    return (short)(__float_as_uint(f) >> 16);
}

static constexpr int B_ = 4, S_ = 2048, D_ = 1024, H_ = 16, DH_ = 64;
// Q pre-scale: 1/sqrt(DH) * log2(e), so attention scores are in log2 domain
static constexpr float QSCALE = 0.125f * 1.4426950408889634f;

// ---------------------------------------------------------------------------
// x convert: f32 -> bf16, 8 elements/thread
// ---------------------------------------------------------------------------
__global__ __launch_bounds__(256) void convert_x(const float* __restrict__ in,
                                                 short* __restrict__ out, int n8) {
    int i = blockIdx.x * 256 + threadIdx.x;
    if (i >= n8) return;
    const float4* p = (const float4*)(in + (size_t)i * 8);
    float4 a = p[0], b = p[1];
    short8 v;
    v[0] = f2bf(a.x); v[1] = f2bf(a.y); v[2] = f2bf(a.z); v[3] = f2bf(a.w);
    v[4] = f2bf(b.x); v[5] = f2bf(b.y); v[6] = f2bf(b.z); v[7] = f2bf(b.w);
    *(short8*)(out + (size_t)i * 8) = v;
}

// ---------------------------------------------------------------------------
// Merged weight prep: transpose + f32->bf16 for Wq/Wk/Wv (z=0..2, y=head) and
// Wo (z=3, y=n-tile). grid (16, 16, 4).
// ---------------------------------------------------------------------------
__global__ __launch_bounds__(256) void prep_weights(const float* __restrict__ Wq,
                                                    const float* __restrict__ Wk,
                                                    const float* __restrict__ Wv,
                                                    const float* __restrict__ Wo,
                                                    short* __restrict__ WqT,
                                                    short* __restrict__ WkT,
                                                    short* __restrict__ WvT,
                                                    short* __restrict__ WoT) {
    __shared__ alignas(16) float t[64 * 68];
    int z = blockIdx.z;
    const float* in;
    short* out;
    int N, M = D_, n0;
    if (z < 3) {
        const float* I = (z == 0) ? Wq : (z == 1) ? Wk : Wv;
        short* O = (z == 0) ? WqT : (z == 1) ? WkT : WvT;
        in = I + (size_t)blockIdx.y * D_ * DH_;
        out = O + (size_t)blockIdx.y * D_ * DH_;
        N = DH_; n0 = 0;
    } else {
        in = Wo; out = WoT; N = D_; n0 = blockIdx.y * 64;
    }
    int m0 = blockIdx.x * 64;
    int tid = threadIdx.x;
#pragma unroll
    for (int i = 0; i < 4; ++i) {
        int c = tid + i * 256;
        int row = c >> 4, c4 = (c & 15) * 4;
        float4 v = *(const float4*)(in + (size_t)(m0 + row) * N + n0 + c4);
        *(float4*)(t + row * 68 + c4) = v;
    }
    __syncthreads();
#pragma unroll
    for (int i = 0; i < 2; ++i) {
        int c = tid + i * 256;
        int row = c >> 3, c8 = (c & 7) * 8;
        short8 v;
#pragma unroll
        for (int j = 0; j < 8; ++j) v[j] = f2bf(t[(c8 + j) * 68 + row]);
        *(short8*)(out + (size_t)(n0 + row) * M + m0 + c8) = v;
    }
}

// ---------------------------------------------------------------------------
// m97-style 128x128 GEMM core with XOR-swizzled LDS chunks (validated r6:
// conflicts 1.9e7 -> 2e5).
// ---------------------------------------------------------------------------
__device__ __forceinline__ void gemm128_core(const short* __restrict__ A,
                                             const short* __restrict__ Bm,
                                             short* ldsA, short* ldsB,
                                             int m0, int n0,
                                             floatx4 (&acc)[4][4],
                                             int w, int lane, int quad, int lm) {
    const int K = 1024;
    int wm = (w >> 1) * 64, wn = (w & 1) * 64;
    int rsub = lane >> 3;                       // row-within-8-group
    int csw = ((lane & 7) ^ rsub) * 8;          // swizzled global k-chunk offset (shorts)
    int lmx = lm & 7;                           // reader swizzle key
    for (int k0 = 0; k0 < K; k0 += 64) {
#pragma unroll
        for (int i = 0; i < 4; ++i) {
            int r0 = w * 32 + i * 8;
            const short* ga = A + (size_t)(m0 + r0 + rsub) * K + k0 + csw;
            __builtin_amdgcn_global_load_lds((const __attribute__((address_space(1))) void*)ga,
                                             (__attribute__((address_space(3))) void*)(ldsA + r0 * 64),
                                             16, 0, 0);
            const short* gb = Bm + (size_t)(n0 + r0 + rsub) * K + k0 + csw;
            __builtin_amdgcn_global_load_lds((const __attribute__((address_space(1))) void*)gb,
                                             (__attribute__((address_space(3))) void*)(ldsB + r0 * 64),
                                             16, 0, 0);
        }
        __syncthreads();
#pragma unroll
        for (int ks = 0; ks < 2; ++ks) {
            short8 am[4], bn[4];
#pragma unroll
            for (int i = 0; i < 4; ++i)
                am[i] = *(const short8*)(ldsA + (wm + i * 16 + lm) * 64 + (((ks * 4 + quad) ^ lmx) << 3));
#pragma unroll
            for (int i = 0; i < 4; ++i)
                bn[i] = *(const short8*)(ldsB + (wn + i * 16 + lm) * 64 + (((ks * 4 + quad) ^ lmx) << 3));
#pragma unroll
            for (int mi = 0; mi < 4; ++mi)
#pragma unroll
                for (int ni = 0; ni < 4; ++ni)
                    acc[mi][ni] = __builtin_amdgcn_mfma_f32_16x16x32_bf16(am[mi], bn[ni], acc[mi][ni], 0, 0, 0);
        }
        __syncthreads();
    }
}

// ---------------------------------------------------------------------------
// QKV projection: grid (64, 8, 3). A = xb [8192][1024]. B = W?T [1024 n][1024 k].
// z=0 -> Q[b,h,s,e] pre-scaled by QSCALE; z=1 -> K[b,h,s,e]; z=2 -> VT[(b*1024+n)][s]
// ---------------------------------------------------------------------------
__global__ __launch_bounds__(256, 4) void qkv_gemm128(const short* __restrict__ xb,
                                                      const short* __restrict__ WqT,
                                                      const short* __restrict__ WkT,
                                                      const short* __restrict__ WvT,
                                                      short* __restrict__ Q,
                                                      short* __restrict__ K,
                                                      short* __restrict__ VT) {
    __shared__ alignas(16) short lds[16384];  // 32 KB: staging A|B, reused as epilogue bounce
    short* ldsA = lds;
    short* ldsB = lds + 8192;
    int m0 = blockIdx.x * 128, n0 = blockIdx.y * 128, z = blockIdx.z;
    const short* Bm = (z == 0) ? WqT : (z == 1) ? WkT : WvT;
    int tid = threadIdx.x, w = tid >> 6, lane = tid & 63, quad = lane >> 4, lm = lane & 15;

    floatx4 acc[4][4];
#pragma unroll
    for (int mi = 0; mi < 4; ++mi)
#pragma unroll
        for (int ni = 0; ni < 4; ++ni) acc[mi][ni] = (floatx4)0.0f;

    gemm128_core(xb, Bm, ldsA, ldsB, m0, n0, acc, w, lane, quad, lm);

    int wm = (w >> 1) * 64, wn = (w & 1) * 64;
    int b = m0 >> 11;
    int sbase = m0 & 2047;

    if (z < 2) {
        short* O = (z == 0) ? Q : K;
        float scale = (z == 0) ? QSCALE : 1.0f;
        short* t = lds;  // 128 x 68
#pragma unroll
        for (int ph = 0; ph < 2; ++ph) {
            if (ph) __syncthreads();
            if ((w & 1) == ph) {
#pragma unroll
                for (int mi = 0; mi < 4; ++mi)
#pragma unroll
                    for (int ni = 0; ni < 4; ++ni)
#pragma unroll
                        for (int r = 0; r < 4; ++r)
                            t[(wm + mi * 16 + quad * 4 + r) * 68 + ni * 16 + lm] =
                                f2bf(acc[mi][ni][r] * scale);
            }
            __syncthreads();
            int h = (n0 + ph * 64) >> 6;
            size_t obase = ((size_t)(b * 16 + h) * 2048 + sbase) * 64;
#pragma unroll
            for (int i = 0; i < 4; ++i) {
                int c = tid + i * 256;
                int m = c >> 3, e8 = (c & 7) * 8;
                short8 v = *(const short8*)(t + m * 68 + e8);
                *(short8*)(O + obase + (size_t)m * 64 + e8) = v;
            }
        }
    } else {
        // transpose 128x128 tile through LDS (two 64-n halves) -> VT[b*1024+n][s]
        short* t = lds;  // 64 x 136
#pragma unroll
        for (int ph = 0; ph < 2; ++ph) {
            if (ph) __syncthreads();
            if ((w & 1) == ph) {
#pragma unroll
                for (int mi = 0; mi < 4; ++mi)
#pragma unroll
                    for (int ni = 0; ni < 4; ++ni) {
                        int nl = ni * 16 + lm;
#pragma unroll
                        for (int r = 0; r < 4; ++r) {
                            int ml = wm + mi * 16 + quad * 4 + r;
                            t[nl * 136 + ml] = f2bf(acc[mi][ni][r]);
                        }
                    }
            }
            __syncthreads();
#pragma unroll
            for (int i = 0; i < 4; ++i) {
                int c = tid + i * 256;
                int rowl = c >> 4, colc = (c & 15) * 8;
                short8 v = *(const short8*)(t + rowl * 136 + colc);
                size_t n = n0 + ph * 64 + rowl;
                *(short8*)(VT + ((size_t)b * 1024 + n) * 2048 + sbase + colc) = v;
            }
        }
    }
}

// ---------------------------------------------------------------------------
// Output projection: out[8192][1024] f32 = CC @ WoT^T + bo. grid (64, 8).
// ---------------------------------------------------------------------------
__global__ __launch_bounds__(256, 4) void outproj128(const short* __restrict__ CC,
                                                     const short* __restrict__ WoT,
                                                     const float* __restrict__ bo,
                                                     float* __restrict__ out) {
    __shared__ alignas(16) short lds[16384];
    short* ldsA = lds;
    short* ldsB = lds + 8192;
    int m0 = blockIdx.x * 128, n0 = blockIdx.y * 128;
    int tid = threadIdx.x, w = tid >> 6, lane = tid & 63, quad = lane >> 4, lm = lane & 15;

    floatx4 acc[4][4];
#pragma unroll
    for (int mi = 0; mi < 4; ++mi)
#pragma unroll
        for (int ni = 0; ni < 4; ++ni) acc[mi][ni] = (floatx4)0.0f;

    gemm128_core(CC, WoT, ldsA, ldsB, m0, n0, acc, w, lane, quad, lm);

    int wm = (w >> 1) * 64, wn = (w & 1) * 64;
#pragma unroll
    for (int mi = 0; mi < 4; ++mi)
#pragma unroll
        for (int ni = 0; ni < 4; ++ni) {
            int n = n0 + wn + ni * 16 + lm;
            float bb = bo[n];
#pragma unroll
            for (int r = 0; r < 4; ++r) {
                int m = m0 + wm + mi * 16 + quad * 4 + r;
                out[(size_t)m * 1024 + n] = acc[mi][ni][r] + bb;
            }
        }
}

// ---------------------------------------------------------------------------
// Causal flash attention v10 = v9 (78.0 us, FETCH 30 MB via XCD-aware grid)
// + T14 async-STAGE split. r6 diagnosis: not memory-bound (HBM 7.6%), not
// MFMA-bound (19%); ~half of each k-tile is the exposed stage->barrier drain
// (global_load_lds latency sits between barriers, only 2 blocks/CU to cover).
// v10 k-loop: issue tile kt+1's K/V global loads into REGISTERS (8 dwordx4/
// thread, +32 VGPR; cap at (256,2) is 256 so no spill) at the TOP of iter kt,
// compute kt, then barrier -> ds_write regs -> barrier. Load latency hides
// under the ~2000-cyc compute phase. Same swizzled global addresses + linear
// LDS dests as the gload_lds path (rule #21 both-sides-or-neither preserved).
// Tile 0 still staged via global_load_lds (no overlap opportunity).
// LDS: Kt 16K + Vt 16K + Pt 32K = 64 KB -> 2 blocks/CU.
// ---------------------------------------------------------------------------
__global__ __launch_bounds__(256, 2) void attn_kernel(const short* __restrict__ Q,
                                                      const short* __restrict__ Kb,
                                                      const short* __restrict__ VT,
                                                      short* __restrict__ CC) {
    __shared__ alignas(16) short Kt[128 * 64];   // swizzled chunks
    __shared__ alignas(16) short Vt[64 * 128];   // swizzled chunks
    __shared__ alignas(16) short Pt[128 * 128];  // swizzled chunks
    int bh = blockIdx.x;
    int pi = blockIdx.y;
    int b = bh >> 4, h = bh & 15;
    int tid = threadIdx.x;
    int w = tid >> 6, l = tid & 63;
    int quad = l >> 4, lm = l & 15;
    int lmx = lm & 7;
    int rsub = l >> 3;              // K staging row-within-8
    int csw = ((l & 7) ^ rsub) * 8; // K staging swizzled chunk offset
    int vr4 = l >> 4;               // V staging row-within-4
    int vc = l & 15;

    const short* Qbh = Q + (size_t)bh * S_ * DH_;
    const short* Kbh = Kb + (size_t)bh * S_ * DH_;
    const short* Vbh = VT + (size_t)bh * 64 * S_;

    for (int ps = 0; ps < 2; ++ps) {
        int qt = ps ? (15 - pi) : pi;
        int q0 = qt * 128;

        short8 qa[2][2];
#pragma unroll
        for (int nq = 0; nq < 2; ++nq) {
            const short* Qrow = Qbh + (size_t)(q0 + nq * 64 + w * 16 + lm) * DH_;
            qa[nq][0] = *(const short8*)(Qrow + quad * 8);
            qa[nq][1] = *(const short8*)(Qrow + 32 + quad * 8);
        }

        floatx4 acc_o[2][4];
#pragma unroll
        for (int nq = 0; nq < 2; ++nq)
#pragma unroll
            for (int ct = 0; ct < 4; ++ct) acc_o[nq][ct] = (floatx4)0.0f;
        float lsum[2] = {0.0f, 0.0f};

        int nkt = qt + 1;

        // prologue: stage tile 0 via global_load_lds (barrier first protects
        // LDS from ps=0's still-computing waves when ps=1 restages)
        __syncthreads();
#pragma unroll
        for (int i = 0; i < 4; ++i) {
            int r0 = w * 32 + i * 8;
            const short* ga = Kbh + (size_t)(r0 + rsub) * 64 + csw;
            __builtin_amdgcn_global_load_lds((const __attribute__((address_space(1))) void*)ga,
                                             (__attribute__((address_space(3))) void*)(Kt + r0 * 64),
                                             16, 0, 0);
        }
#pragma unroll
        for (int i = 0; i < 4; ++i) {
            int r0v = w * 16 + i * 4;
            int row = r0v + vr4;
            const short* gv = Vbh + (size_t)row * S_ + ((vc ^ (row & 7)) * 8);
            __builtin_amdgcn_global_load_lds((const __attribute__((address_space(1))) void*)gv,
                                             (__attribute__((address_space(3))) void*)(Vt + r0v * 128),
                                             16, 0, 0);
        }
        __syncthreads();

        for (int kt = 0; kt < nkt; ++kt) {
            int t0 = kt * 128;
            bool pf = (kt + 1 < nkt);
            // T14: issue next tile's loads into regs NOW; latency hides under compute
            short8 kpre[4], vpre[4];
            if (pf) {
                int t1 = t0 + 128;
                const short* Ktile = Kbh + (size_t)t1 * DH_;
#pragma unroll
                for (int i = 0; i < 4; ++i) {
                    int r0 = w * 32 + i * 8;
                    kpre[i] = *(const short8*)(Ktile + (size_t)(r0 + rsub) * 64 + csw);
                }
#pragma unroll
                for (int i = 0; i < 4; ++i) {
                    int row = w * 16 + i * 4 + vr4;
                    vpre[i] = *(const short8*)(Vbh + (size_t)row * S_ + t1 + ((vc ^ (row & 7)) * 8));
                }
            }

            // K-frags once, reused for both q-halves
            short8 kf[8][2];
#pragma unroll
            for (int mt = 0; mt < 8; ++mt)
#pragma unroll
                for (int ks = 0; ks < 2; ++ks)
                    kf[mt][ks] = *(const short8*)(Kt + (mt * 16 + lm) * 64 + (((ks * 4 + quad) ^ lmx) << 3));

            bool last = (kt == nkt - 1);
#pragma unroll
            for (int nq = 0; nq < 2; ++nq) {
                floatx4 sc[8];
                __builtin_amdgcn_s_setprio(1);
#pragma unroll
                for (int mt = 0; mt < 8; ++mt) {
                    floatx4 t = (floatx4)0.0f;
                    t = __builtin_amdgcn_mfma_f32_16x16x32_bf16(kf[mt][0], qa[nq][0], t, 0, 0, 0);
                    t = __builtin_amdgcn_mfma_f32_16x16x32_bf16(kf[mt][1], qa[nq][1], t, 0, 0, 0);
                    sc[mt] = t;  // S^T: row=t (quad*4+r), col=q (lm)
                }
                __builtin_amdgcn_s_setprio(0);
                if (last) {
                    int q_ = q0 + nq * 64 + w * 16 + lm;
#pragma unroll
                    for (int mt = 0; mt < 8; ++mt)
#pragma unroll
                        for (int r = 0; r < 4; ++r) {
                            int t_ = t0 + mt * 16 + quad * 4 + r;
                            if (t_ > q_) sc[mt][r] = -INFINITY;
                        }
                }
                int prow = nq * 64 + w * 16 + lm;
#pragma unroll
                for (int mt = 0; mt < 8; ++mt) {
                    float p0 = exp2f(sc[mt][0]);
                    float p1 = exp2f(sc[mt][1]);
                    float p2 = exp2f(sc[mt][2]);
                    float p3 = exp2f(sc[mt][3]);
                    lsum[nq] += (p0 + p1) + (p2 + p3);
                    short4x pk;
                    pk[0] = f2bf_rz(p0); pk[1] = f2bf_rz(p1);
                    pk[2] = f2bf_rz(p2); pk[3] = f2bf_rz(p3);
                    int c = mt * 2 + (quad >> 1);
                    *(short4x*)(Pt + prow * 128 + ((c ^ lmx) << 3) + (quad & 1) * 4) = pk;
                }
            }
            // Pt rows are wave-private -> no barrier between write and read
            short8 pa[2][4];
#pragma unroll
            for (int nq = 0; nq < 2; ++nq)
#pragma unroll
                for (int ks = 0; ks < 4; ++ks)
                    pa[nq][ks] = *(const short8*)(Pt + (nq * 64 + w * 16 + lm) * 128 +
                                                  (((ks * 4 + quad) ^ lmx) << 3));
            __builtin_amdgcn_s_setprio(1);
#pragma unroll
            for (int ct = 0; ct < 4; ++ct) {
                const short* vrow = Vt + (ct * 16 + lm) * 128;
#pragma unroll
                for (int ks = 0; ks < 4; ++ks) {
                    short8 v = *(const short8*)(vrow + (((ks * 4 + quad) ^ lmx) << 3));
                    acc_o[0][ct] = __builtin_amdgcn_mfma_f32_16x16x32_bf16(pa[0][ks], v, acc_o[0][ct], 0, 0, 0);
                    acc_o[1][ct] = __builtin_amdgcn_mfma_f32_16x16x32_bf16(pa[1][ks], v, acc_o[1][ct], 0, 0, 0);
                }
            }
            __builtin_amdgcn_s_setprio(0);

            if (pf) {
                __syncthreads();  // all waves done reading Kt/Vt for tile kt
#pragma unroll
                for (int i = 0; i < 4; ++i) {
                    int r0 = w * 32 + i * 8;
                    *(short8*)(Kt + r0 * 64 + l * 8) = kpre[i];
                }
#pragma unroll
                for (int i = 0; i < 4; ++i) {
                    int r0v = w * 16 + i * 4;
                    *(short8*)(Vt + r0v * 128 + l * 8) = vpre[i];
                }
                __syncthreads();  // tile kt+1 visible to all waves
            }
        }

        // reduce l across quads (lanes with same lm), then 1/l
        float invl[2];
#pragma unroll
        for (int nq = 0; nq < 2; ++nq) {
            float lr = lsum[nq];
            lr += __shfl_xor(lr, 16);
            lr += __shfl_xor(lr, 32);
            invl[nq] = 1.0f / lr;
        }

#pragma unroll
        for (int nq = 0; nq < 2; ++nq) {
#pragma unroll
            for (int r = 0; r < 4; ++r) {
                float iv = __shfl(invl[nq], quad * 4 + r);  // l for q-row quad*4+r
                int row = q0 + nq * 64 + w * 16 + quad * 4 + r;
                short* OC = CC + ((size_t)b * S_ + row) * D_ + h * DH_;
#pragma unroll
                for (int ct = 0; ct < 4; ++ct)
                    OC[ct * 16 + lm] = f2bf(acc_o[nq][ct][r] * iv);
            }
        }
    }
}

extern "C" void kernel_launch(void* const* d_in, const int* in_sizes, int n_in,
                              void* d_out, int out_size, void* d_ws, size_t ws_size,
                              hipStream_t stream) {
    const float* x  = (const float*)d_in[0];
    const float* Wq = (const float*)d_in[1];
    const float* Wk = (const float*)d_in[2];
    const float* Wv = (const float*)d_in[3];
    const float* Wo = (const float*)d_in[4];
    const float* bo = (const float*)d_in[5];
    float* out = (float*)d_out;
    short* ws = (short*)d_ws;

    const size_t WSZ = (size_t)H_ * D_ * DH_;        // 1,048,576
    const size_t QSZ = (size_t)B_ * H_ * S_ * DH_;   // 8,388,608
    short* WqT = ws;
    short* WkT = WqT + WSZ;
    short* WvT = WkT + WSZ;
    short* WoT = WvT + WSZ;
    short* xb  = WoT + (size_t)D_ * D_;
    short* Qb  = xb + (size_t)B_ * S_ * D_;
    short* Kb  = Qb + QSZ;
    short* VTb = Kb + QSZ;
    short* CCb = VTb + QSZ;

    convert_x<<<(B_ * S_ * D_ / 8 + 255) / 256, 256, 0, stream>>>(x, xb, B_ * S_ * D_ / 8);
    prep_weights<<<dim3(16, 16, 4), 256, 0, stream>>>(Wq, Wk, Wv, Wo, WqT, WkT, WvT, WoT);
    qkv_gemm128<<<dim3(64, 8, 3), 256, 0, stream>>>(xb, WqT, WkT, WvT, Qb, Kb, VTb);
    attn_kernel<<<dim3(64, 8), 256, 0, stream>>>(Qb, Kb, VTb, CCb);
    outproj128<<<dim3(64, 8), 256, 0, stream>>>(CCb, WoT, bo, out);
}

// Round 8
// 243.034 us; speedup vs baseline: 1.0321x; 1.0321x over previous
//
#include <hip/hip_runtime.h>
#include <hip/hip_bf16.h>

typedef __attribute__((ext_vector_type(8))) short short8;
typedef __attribute__((ext_vector_type(4))) short short4x;
typedef __attribute__((ext_vector_type(4))) float floatx4;

__device__ __forceinline__ short f2bf(float f) {
    unsigned u = __float_as_uint(f);
    u = u + 0x7fffu + ((u >> 16) & 1u);
    return (short)(u >> 16);
}
// truncating convert (values >=0, used for P only)
__device__ __forceinline__ short f2bf_rz(float f) {
    return (short)(__float_as_uint(f) >> 16);
}

static constexpr int B_ = 4, S_ = 2048, D_ = 1024, H_ = 16, DH_ = 64;
// Q pre-scale: 1/sqrt(DH) * log2(e), so attention scores are in log2 domain
static constexpr float QSCALE = 0.125f * 1.4426950408889634f;

// ---------------------------------------------------------------------------
// x convert: f32 -> bf16, 8 elements/thread
// ---------------------------------------------------------------------------
__global__ __launch_bounds__(256) void convert_x(const float* __restrict__ in,
                                                 short* __restrict__ out, int n8) {
    int i = blockIdx.x * 256 + threadIdx.x;
    if (i >= n8) return;
    const float4* p = (const float4*)(in + (size_t)i * 8);
    float4 a = p[0], b = p[1];
    short8 v;
    v[0] = f2bf(a.x); v[1] = f2bf(a.y); v[2] = f2bf(a.z); v[3] = f2bf(a.w);
    v[4] = f2bf(b.x); v[5] = f2bf(b.y); v[6] = f2bf(b.z); v[7] = f2bf(b.w);
    *(short8*)(out + (size_t)i * 8) = v;
}

// ---------------------------------------------------------------------------
// Merged weight prep: transpose + f32->bf16 for Wq/Wk/Wv (z=0..2, y=head) and
// Wo (z=3, y=n-tile). grid (16, 16, 4).
// ---------------------------------------------------------------------------
__global__ __launch_bounds__(256) void prep_weights(const float* __restrict__ Wq,
                                                    const float* __restrict__ Wk,
                                                    const float* __restrict__ Wv,
                                                    const float* __restrict__ Wo,
                                                    short* __restrict__ WqT,
                                                    short* __restrict__ WkT,
                                                    short* __restrict__ WvT,
                                                    short* __restrict__ WoT) {
    __shared__ alignas(16) float t[64 * 68];
    int z = blockIdx.z;
    const float* in;
    short* out;
    int N, M = D_, n0;
    if (z < 3) {
        const float* I = (z == 0) ? Wq : (z == 1) ? Wk : Wv;
        short* O = (z == 0) ? WqT : (z == 1) ? WkT : WvT;
        in = I + (size_t)blockIdx.y * D_ * DH_;
        out = O + (size_t)blockIdx.y * D_ * DH_;
        N = DH_; n0 = 0;
    } else {
        in = Wo; out = WoT; N = D_; n0 = blockIdx.y * 64;
    }
    int m0 = blockIdx.x * 64;
    int tid = threadIdx.x;
#pragma unroll
    for (int i = 0; i < 4; ++i) {
        int c = tid + i * 256;
        int row = c >> 4, c4 = (c & 15) * 4;
        float4 v = *(const float4*)(in + (size_t)(m0 + row) * N + n0 + c4);
        *(float4*)(t + row * 68 + c4) = v;
    }
    __syncthreads();
#pragma unroll
    for (int i = 0; i < 2; ++i) {
        int c = tid + i * 256;
        int row = c >> 3, c8 = (c & 7) * 8;
        short8 v;
#pragma unroll
        for (int j = 0; j < 8; ++j) v[j] = f2bf(t[(c8 + j) * 68 + row]);
        *(short8*)(out + (size_t)(n0 + row) * M + m0 + c8) = v;
    }
}

// ---------------------------------------------------------------------------
// m97-style 128x128 GEMM core with XOR-swizzled LDS chunks (validated r6:
// conflicts 1.9e7 -> 2e5).
// ---------------------------------------------------------------------------
__device__ __forceinline__ void gemm128_core(const short* __restrict__ A,
                                             const short* __restrict__ Bm,
                                             short* ldsA, short* ldsB,
                                             int m0, int n0,
                                             floatx4 (&acc)[4][4],
                                             int w, int lane, int quad, int lm) {
    const int K = 1024;
    int wm = (w >> 1) * 64, wn = (w & 1) * 64;
    int rsub = lane >> 3;                       // row-within-8-group
    int csw = ((lane & 7) ^ rsub) * 8;          // swizzled global k-chunk offset (shorts)
    int lmx = lm & 7;                           // reader swizzle key
    for (int k0 = 0; k0 < K; k0 += 64) {
#pragma unroll
        for (int i = 0; i < 4; ++i) {
            int r0 = w * 32 + i * 8;
            const short* ga = A + (size_t)(m0 + r0 + rsub) * K + k0 + csw;
            __builtin_amdgcn_global_load_lds((const __attribute__((address_space(1))) void*)ga,
                                             (__attribute__((address_space(3))) void*)(ldsA + r0 * 64),
                                             16, 0, 0);
            const short* gb = Bm + (size_t)(n0 + r0 + rsub) * K + k0 + csw;
            __builtin_amdgcn_global_load_lds((const __attribute__((address_space(1))) void*)gb,
                                             (__attribute__((address_space(3))) void*)(ldsB + r0 * 64),
                                             16, 0, 0);
        }
        __syncthreads();
#pragma unroll
        for (int ks = 0; ks < 2; ++ks) {
            short8 am[4], bn[4];
#pragma unroll
            for (int i = 0; i < 4; ++i)
                am[i] = *(const short8*)(ldsA + (wm + i * 16 + lm) * 64 + (((ks * 4 + quad) ^ lmx) << 3));
#pragma unroll
            for (int i = 0; i < 4; ++i)
                bn[i] = *(const short8*)(ldsB + (wn + i * 16 + lm) * 64 + (((ks * 4 + quad) ^ lmx) << 3));
#pragma unroll
            for (int mi = 0; mi < 4; ++mi)
#pragma unroll
                for (int ni = 0; ni < 4; ++ni)
                    acc[mi][ni] = __builtin_amdgcn_mfma_f32_16x16x32_bf16(am[mi], bn[ni], acc[mi][ni], 0, 0, 0);
        }
        __syncthreads();
    }
}

// ---------------------------------------------------------------------------
// QKV projection: grid (64, 8, 3). A = xb [8192][1024]. B = W?T [1024 n][1024 k].
// z=0 -> Q[b,h,s,e] pre-scaled by QSCALE; z=1 -> K[b,h,s,e]; z=2 -> VT[(b*1024+n)][s]
// r7: launch_bounds (256,4)->(256,3). The (256,4) 128-VGPR cap strangled the
// m97-style core (reference needs ~164 VGPR at 3 blocks/CU); (256,3) restores
// the m97 register regime. LDS 32K allows 5 blocks so LDS is not the limiter.
// ---------------------------------------------------------------------------
__global__ __launch_bounds__(256, 3) void qkv_gemm128(const short* __restrict__ xb,
                                                      const short* __restrict__ WqT,
                                                      const short* __restrict__ WkT,
                                                      const short* __restrict__ WvT,
                                                      short* __restrict__ Q,
                                                      short* __restrict__ K,
                                                      short* __restrict__ VT) {
    __shared__ alignas(16) short lds[16384];  // 32 KB: staging A|B, reused as epilogue bounce
    short* ldsA = lds;
    short* ldsB = lds + 8192;
    int m0 = blockIdx.x * 128, n0 = blockIdx.y * 128, z = blockIdx.z;
    const short* Bm = (z == 0) ? WqT : (z == 1) ? WkT : WvT;
    int tid = threadIdx.x, w = tid >> 6, lane = tid & 63, quad = lane >> 4, lm = lane & 15;

    floatx4 acc[4][4];
#pragma unroll
    for (int mi = 0; mi < 4; ++mi)
#pragma unroll
        for (int ni = 0; ni < 4; ++ni) acc[mi][ni] = (floatx4)0.0f;

    gemm128_core(xb, Bm, ldsA, ldsB, m0, n0, acc, w, lane, quad, lm);

    int wm = (w >> 1) * 64, wn = (w & 1) * 64;
    int b = m0 >> 11;
    int sbase = m0 & 2047;

    if (z < 2) {
        short* O = (z == 0) ? Q : K;
        float scale = (z == 0) ? QSCALE : 1.0f;
        short* t = lds;  // 128 x 68
#pragma unroll
        for (int ph = 0; ph < 2; ++ph) {
            if (ph) __syncthreads();
            if ((w & 1) == ph) {
#pragma unroll
                for (int mi = 0; mi < 4; ++mi)
#pragma unroll
                    for (int ni = 0; ni < 4; ++ni)
#pragma unroll
                        for (int r = 0; r < 4; ++r)
                            t[(wm + mi * 16 + quad * 4 + r) * 68 + ni * 16 + lm] =
                                f2bf(acc[mi][ni][r] * scale);
            }
            __syncthreads();
            int h = (n0 + ph * 64) >> 6;
            size_t obase = ((size_t)(b * 16 + h) * 2048 + sbase) * 64;
#pragma unroll
            for (int i = 0; i < 4; ++i) {
                int c = tid + i * 256;
                int m = c >> 3, e8 = (c & 7) * 8;
                short8 v = *(const short8*)(t + m * 68 + e8);
                *(short8*)(O + obase + (size_t)m * 64 + e8) = v;
            }
        }
    } else {
        // transpose 128x128 tile through LDS (two 64-n halves) -> VT[b*1024+n][s]
        short* t = lds;  // 64 x 136
#pragma unroll
        for (int ph = 0; ph < 2; ++ph) {
            if (ph) __syncthreads();
            if ((w & 1) == ph) {
#pragma unroll
                for (int mi = 0; mi < 4; ++mi)
#pragma unroll
                    for (int ni = 0; ni < 4; ++ni) {
                        int nl = ni * 16 + lm;
#pragma unroll
                        for (int r = 0; r < 4; ++r) {
                            int ml = wm + mi * 16 + quad * 4 + r;
                            t[nl * 136 + ml] = f2bf(acc[mi][ni][r]);
                        }
                    }
            }
            __syncthreads();
#pragma unroll
            for (int i = 0; i < 4; ++i) {
                int c = tid + i * 256;
                int rowl = c >> 4, colc = (c & 15) * 8;
                short8 v = *(const short8*)(t + rowl * 136 + colc);
                size_t n = n0 + ph * 64 + rowl;
                *(short8*)(VT + ((size_t)b * 1024 + n) * 2048 + sbase + colc) = v;
            }
        }
    }
}

// ---------------------------------------------------------------------------
// Output projection: out[8192][1024] f32 = CC @ WoT^T + bo. grid (64, 8).
// r7: launch_bounds (256,4)->(256,3). Grid is 512 blocks = 2 blocks/CU anyway,
// so this ONLY raises the VGPR cap 128->168 (pure upside if the core was
// register-starved).
// ---------------------------------------------------------------------------
__global__ __launch_bounds__(256, 3) void outproj128(const short* __restrict__ CC,
                                                     const short* __restrict__ WoT,
                                                     const float* __restrict__ bo,
                                                     float* __restrict__ out) {
    __shared__ alignas(16) short lds[16384];
    short* ldsA = lds;
    short* ldsB = lds + 8192;
    int m0 = blockIdx.x * 128, n0 = blockIdx.y * 128;
    int tid = threadIdx.x, w = tid >> 6, lane = tid & 63, quad = lane >> 4, lm = lane & 15;

    floatx4 acc[4][4];
#pragma unroll
    for (int mi = 0; mi < 4; ++mi)
#pragma unroll
        for (int ni = 0; ni < 4; ++ni) acc[mi][ni] = (floatx4)0.0f;

    gemm128_core(CC, WoT, ldsA, ldsB, m0, n0, acc, w, lane, quad, lm);

    int wm = (w >> 1) * 64, wn = (w & 1) * 64;
#pragma unroll
    for (int mi = 0; mi < 4; ++mi)
#pragma unroll
        for (int ni = 0; ni < 4; ++ni) {
            int n = n0 + wn + ni * 16 + lm;
            float bb = bo[n];
#pragma unroll
            for (int r = 0; r < 4; ++r) {
                int m = m0 + wm + mi * 16 + quad * 4 + r;
                out[(size_t)m * 1024 + n] = acc[mi][ni][r] + bb;
            }
        }
}

// ---------------------------------------------------------------------------
// Causal flash attention v9 (REVERTED from r7's T14 experiment, which cost
// +15% — matching the guide's m249 note that reg-staging costs ~16% vs
// global_load_lds; attn's LDS pipe is 60-85% busy so added ds_writes lose).
// Round-0 structure (78.0 us) + XCD-aware grid: bh fastest-varying pins each
// bh's K/V to one XCD L2 (measured FETCH 146 -> 30 MB).
// s_setprio(1) around MFMA clusters (T5).
// LDS: Kt 16K + Vt 16K + Pt 32K = 64 KB -> 2 blocks/CU.
// ---------------------------------------------------------------------------
__global__ __launch_bounds__(256, 2) void attn_kernel(const short* __restrict__ Q,
                                                      const short* __restrict__ Kb,
                                                      const short* __restrict__ VT,
                                                      short* __restrict__ CC) {
    __shared__ alignas(16) short Kt[128 * 64];   // swizzled chunks
    __shared__ alignas(16) short Vt[64 * 128];   // swizzled chunks
    __shared__ alignas(16) short Pt[128 * 128];  // swizzled chunks
    int bh = blockIdx.x;
    int pi = blockIdx.y;
    int b = bh >> 4, h = bh & 15;
    int tid = threadIdx.x;
    int w = tid >> 6, l = tid & 63;
    int quad = l >> 4, lm = l & 15;
    int lmx = lm & 7;
    int rsub = l >> 3;              // K staging row-within-8
    int csw = ((l & 7) ^ rsub) * 8; // K staging swizzled chunk offset
    int vr4 = l >> 4;               // V staging row-within-4
    int vc = l & 15;

    const short* Qbh = Q + (size_t)bh * S_ * DH_;
    const short* Kbh = Kb + (size_t)bh * S_ * DH_;
    const short* Vbh = VT + (size_t)bh * 64 * S_;

    for (int ps = 0; ps < 2; ++ps) {
        int qt = ps ? (15 - pi) : pi;
        int q0 = qt * 128;

        short8 qa[2][2];
#pragma unroll
        for (int nq = 0; nq < 2; ++nq) {
            const short* Qrow = Qbh + (size_t)(q0 + nq * 64 + w * 16 + lm) * DH_;
            qa[nq][0] = *(const short8*)(Qrow + quad * 8);
            qa[nq][1] = *(const short8*)(Qrow + 32 + quad * 8);
        }

        floatx4 acc_o[2][4];
#pragma unroll
        for (int nq = 0; nq < 2; ++nq)
#pragma unroll
            for (int ct = 0; ct < 4; ++ct) acc_o[nq][ct] = (floatx4)0.0f;
        float lsum[2] = {0.0f, 0.0f};

        int nkt = qt + 1;
        for (int kt = 0; kt < nkt; ++kt) {
            int t0 = kt * 128;
            // stage Kt[128][64] (rows contiguous) and Vt[64][128] (rows stride S_)
            const short* Ktile = Kbh + (size_t)t0 * DH_;
#pragma unroll
            for (int i = 0; i < 4; ++i) {
                int r0 = w * 32 + i * 8;
                const short* ga = Ktile + (size_t)(r0 + rsub) * 64 + csw;
                __builtin_amdgcn_global_load_lds((const __attribute__((address_space(1))) void*)ga,
                                                 (__attribute__((address_space(3))) void*)(Kt + r0 * 64),
                                                 16, 0, 0);
            }
#pragma unroll
            for (int i = 0; i < 4; ++i) {
                int r0v = w * 16 + i * 4;
                int row = r0v + vr4;
                const short* gv = Vbh + (size_t)row * S_ + t0 + ((vc ^ (row & 7)) * 8);
                __builtin_amdgcn_global_load_lds((const __attribute__((address_space(1))) void*)gv,
                                                 (__attribute__((address_space(3))) void*)(Vt + r0v * 128),
                                                 16, 0, 0);
            }
            __syncthreads();

            // K-frags once, reused for both q-halves
            short8 kf[8][2];
#pragma unroll
            for (int mt = 0; mt < 8; ++mt)
#pragma unroll
                for (int ks = 0; ks < 2; ++ks)
                    kf[mt][ks] = *(const short8*)(Kt + (mt * 16 + lm) * 64 + (((ks * 4 + quad) ^ lmx) << 3));

            bool last = (kt == nkt - 1);
#pragma unroll
            for (int nq = 0; nq < 2; ++nq) {
                floatx4 sc[8];
                __builtin_amdgcn_s_setprio(1);
#pragma unroll
                for (int mt = 0; mt < 8; ++mt) {
                    floatx4 t = (floatx4)0.0f;
                    t = __builtin_amdgcn_mfma_f32_16x16x32_bf16(kf[mt][0], qa[nq][0], t, 0, 0, 0);
                    t = __builtin_amdgcn_mfma_f32_16x16x32_bf16(kf[mt][1], qa[nq][1], t, 0, 0, 0);
                    sc[mt] = t;  // S^T: row=t (quad*4+r), col=q (lm)
                }
                __builtin_amdgcn_s_setprio(0);
                if (last) {
                    int q_ = q0 + nq * 64 + w * 16 + lm;
#pragma unroll
                    for (int mt = 0; mt < 8; ++mt)
#pragma unroll
                        for (int r = 0; r < 4; ++r) {
                            int t_ = t0 + mt * 16 + quad * 4 + r;
                            if (t_ > q_) sc[mt][r] = -INFINITY;
                        }
                }
                int prow = nq * 64 + w * 16 + lm;
#pragma unroll
                for (int mt = 0; mt < 8; ++mt) {
                    float p0 = exp2f(sc[mt][0]);
                    float p1 = exp2f(sc[mt][1]);
                    float p2 = exp2f(sc[mt][2]);
                    float p3 = exp2f(sc[mt][3]);
                    lsum[nq] += (p0 + p1) + (p2 + p3);
                    short4x pk;
                    pk[0] = f2bf_rz(p0); pk[1] = f2bf_rz(p1);
                    pk[2] = f2bf_rz(p2); pk[3] = f2bf_rz(p3);
                    int c = mt * 2 + (quad >> 1);
                    *(short4x*)(Pt + prow * 128 + ((c ^ lmx) << 3) + (quad & 1) * 4) = pk;
                }
            }
            // Pt rows are wave-private -> no barrier between write and read
            short8 pa[2][4];
#pragma unroll
            for (int nq = 0; nq < 2; ++nq)
#pragma unroll
                for (int ks = 0; ks < 4; ++ks)
                    pa[nq][ks] = *(const short8*)(Pt + (nq * 64 + w * 16 + lm) * 128 +
                                                  (((ks * 4 + quad) ^ lmx) << 3));
            __builtin_amdgcn_s_setprio(1);
#pragma unroll
            for (int ct = 0; ct < 4; ++ct) {
                const short* vrow = Vt + (ct * 16 + lm) * 128;
#pragma unroll
                for (int ks = 0; ks < 4; ++ks) {
                    short8 v = *(const short8*)(vrow + (((ks * 4 + quad) ^ lmx) << 3));
                    acc_o[0][ct] = __builtin_amdgcn_mfma_f32_16x16x32_bf16(pa[0][ks], v, acc_o[0][ct], 0, 0, 0);
                    acc_o[1][ct] = __builtin_amdgcn_mfma_f32_16x16x32_bf16(pa[1][ks], v, acc_o[1][ct], 0, 0, 0);
                }
            }
            __builtin_amdgcn_s_setprio(0);
            __syncthreads();  // protects Kt/Vt restage next iteration
        }

        // reduce l across quads (lanes with same lm), then 1/l
        float invl[2];
#pragma unroll
        for (int nq = 0; nq < 2; ++nq) {
            float lr = lsum[nq];
            lr += __shfl_xor(lr, 16);
            lr += __shfl_xor(lr, 32);
            invl[nq] = 1.0f / lr;
        }

#pragma unroll
        for (int nq = 0; nq < 2; ++nq) {
#pragma unroll
            for (int r = 0; r < 4; ++r) {
                float iv = __shfl(invl[nq], quad * 4 + r);  // l for q-row quad*4+r
                int row = q0 + nq * 64 + w * 16 + quad * 4 + r;
                short* OC = CC + ((size_t)b * S_ + row) * D_ + h * DH_;
#pragma unroll
                for (int ct = 0; ct < 4; ++ct)
                    OC[ct * 16 + lm] = f2bf(acc_o[nq][ct][r] * iv);
            }
        }
    }
}

extern "C" void kernel_launch(void* const* d_in, const int* in_sizes, int n_in,
                              void* d_out, int out_size, void* d_ws, size_t ws_size,
                              hipStream_t stream) {
    const float* x  = (const float*)d_in[0];
    const float* Wq = (const float*)d_in[1];
    const float* Wk = (const float*)d_in[2];
    const float* Wv = (const float*)d_in[3];
    const float* Wo = (const float*)d_in[4];
    const float* bo = (const float*)d_in[5];
    float* out = (float*)d_out;
    short* ws = (short*)d_ws;

    const size_t WSZ = (size_t)H_ * D_ * DH_;        // 1,048,576
    const size_t QSZ = (size_t)B_ * H_ * S_ * DH_;   // 8,388,608
    short* WqT = ws;
    short* WkT = WqT + WSZ;
    short* WvT = WkT + WSZ;
    short* WoT = WvT + WSZ;
    short* xb  = WoT + (size_t)D_ * D_;
    short* Qb  = xb + (size_t)B_ * S_ * D_;
    short* Kb  = Qb + QSZ;
    short* VTb = Kb + QSZ;
    short* CCb = VTb + QSZ;

    convert_x<<<(B_ * S_ * D_ / 8 + 255) / 256, 256, 0, stream>>>(x, xb, B_ * S_ * D_ / 8);
    prep_weights<<<dim3(16, 16, 4), 256, 0, stream>>>(Wq, Wk, Wv, Wo, WqT, WkT, WvT, WoT);
    qkv_gemm128<<<dim3(64, 8, 3), 256, 0, stream>>>(xb, WqT, WkT, WvT, Qb, Kb, VTb);
    attn_kernel<<<dim3(64, 8), 256, 0, stream>>>(Qb, Kb, VTb, CCb);
    outproj128<<<dim3(64, 8), 256, 0, stream>>>(CCb, WoT, bo, out);
}

// Round 9
// 238.356 us; speedup vs baseline: 1.0524x; 1.0196x over previous
//
#include <hip/hip_runtime.h>
#include <hip/hip_bf16.h>

typedef __attribute__((ext_vector_type(8))) short short8;
typedef __attribute__((ext_vector_type(4))) short short4x;
typedef __attribute__((ext_vector_type(4))) float floatx4;
typedef __attribute__((ext_vector_type(16))) float floatx16;
typedef __attribute__((ext_vector_type(4))) unsigned uintx4;

__device__ __forceinline__ short f2bf(float f) {
    unsigned u = __float_as_uint(f);
    u = u + 0x7fffu + ((u >> 16) & 1u);
    return (short)(u >> 16);
}
// truncating convert (values >=0, used for P only)
__device__ __forceinline__ short f2bf_rz(float f) {
    return (short)(__float_as_uint(f) >> 16);
}

static constexpr int B_ = 4, S_ = 2048, D_ = 1024, H_ = 16, DH_ = 64;
// Q pre-scale: 1/sqrt(DH) * log2(e), so attention scores are in log2 domain
static constexpr float QSCALE = 0.125f * 1.4426950408889634f;

// ---------------------------------------------------------------------------
// x convert: f32 -> bf16, 8 elements/thread
// ---------------------------------------------------------------------------
__global__ __launch_bounds__(256) void convert_x(const float* __restrict__ in,
                                                 short* __restrict__ out, int n8) {
    int i = blockIdx.x * 256 + threadIdx.x;
    if (i >= n8) return;
    const float4* p = (const float4*)(in + (size_t)i * 8);
    float4 a = p[0], b = p[1];
    short8 v;
    v[0] = f2bf(a.x); v[1] = f2bf(a.y); v[2] = f2bf(a.z); v[3] = f2bf(a.w);
    v[4] = f2bf(b.x); v[5] = f2bf(b.y); v[6] = f2bf(b.z); v[7] = f2bf(b.w);
    *(short8*)(out + (size_t)i * 8) = v;
}

// ---------------------------------------------------------------------------
// Merged weight prep: transpose + f32->bf16 for Wq/Wk/Wv (z=0..2, y=head) and
// Wo (z=3, y=n-tile). grid (16, 16, 4).
// ---------------------------------------------------------------------------
__global__ __launch_bounds__(256) void prep_weights(const float* __restrict__ Wq,
                                                    const float* __restrict__ Wk,
                                                    const float* __restrict__ Wv,
                                                    const float* __restrict__ Wo,
                                                    short* __restrict__ WqT,
                                                    short* __restrict__ WkT,
                                                    short* __restrict__ WvT,
                                                    short* __restrict__ WoT) {
    __shared__ alignas(16) float t[64 * 68];
    int z = blockIdx.z;
    const float* in;
    short* out;
    int N, M = D_, n0;
    if (z < 3) {
        const float* I = (z == 0) ? Wq : (z == 1) ? Wk : Wv;
        short* O = (z == 0) ? WqT : (z == 1) ? WkT : WvT;
        in = I + (size_t)blockIdx.y * D_ * DH_;
        out = O + (size_t)blockIdx.y * D_ * DH_;
        N = DH_; n0 = 0;
    } else {
        in = Wo; out = WoT; N = D_; n0 = blockIdx.y * 64;
    }
    int m0 = blockIdx.x * 64;
    int tid = threadIdx.x;
#pragma unroll
    for (int i = 0; i < 4; ++i) {
        int c = tid + i * 256;
        int row = c >> 4, c4 = (c & 15) * 4;
        float4 v = *(const float4*)(in + (size_t)(m0 + row) * N + n0 + c4);
        *(float4*)(t + row * 68 + c4) = v;
    }
    __syncthreads();
#pragma unroll
    for (int i = 0; i < 2; ++i) {
        int c = tid + i * 256;
        int row = c >> 3, c8 = (c & 7) * 8;
        short8 v;
#pragma unroll
        for (int j = 0; j < 8; ++j) v[j] = f2bf(t[(c8 + j) * 68 + row]);
        *(short8*)(out + (size_t)(n0 + row) * M + m0 + c8) = v;
    }
}

// ---------------------------------------------------------------------------
// m97-style 128x128 GEMM core with XOR-swizzled LDS chunks (validated r6:
// conflicts 1.9e7 -> 2e5).
// ---------------------------------------------------------------------------
__device__ __forceinline__ void gemm128_core(const short* __restrict__ A,
                                             const short* __restrict__ Bm,
                                             short* ldsA, short* ldsB,
                                             int m0, int n0,
                                             floatx4 (&acc)[4][4],
                                             int w, int lane, int quad, int lm) {
    const int K = 1024;
    int wm = (w >> 1) * 64, wn = (w & 1) * 64;
    int rsub = lane >> 3;                       // row-within-8-group
    int csw = ((lane & 7) ^ rsub) * 8;          // swizzled global k-chunk offset (shorts)
    int lmx = lm & 7;                           // reader swizzle key
    for (int k0 = 0; k0 < K; k0 += 64) {
#pragma unroll
        for (int i = 0; i < 4; ++i) {
            int r0 = w * 32 + i * 8;
            const short* ga = A + (size_t)(m0 + r0 + rsub) * K + k0 + csw;
            __builtin_amdgcn_global_load_lds((const __attribute__((address_space(1))) void*)ga,
                                             (__attribute__((address_space(3))) void*)(ldsA + r0 * 64),
                                             16, 0, 0);
            const short* gb = Bm + (size_t)(n0 + r0 + rsub) * K + k0 + csw;
            __builtin_amdgcn_global_load_lds((const __attribute__((address_space(1))) void*)gb,
                                             (__attribute__((address_space(3))) void*)(ldsB + r0 * 64),
                                             16, 0, 0);
        }
        __syncthreads();
#pragma unroll
        for (int ks = 0; ks < 2; ++ks) {
            short8 am[4], bn[4];
#pragma unroll
            for (int i = 0; i < 4; ++i)
                am[i] = *(const short8*)(ldsA + (wm + i * 16 + lm) * 64 + (((ks * 4 + quad) ^ lmx) << 3));
#pragma unroll
            for (int i = 0; i < 4; ++i)
                bn[i] = *(const short8*)(ldsB + (wn + i * 16 + lm) * 64 + (((ks * 4 + quad) ^ lmx) << 3));
#pragma unroll
            for (int mi = 0; mi < 4; ++mi)
#pragma unroll
                for (int ni = 0; ni < 4; ++ni)
                    acc[mi][ni] = __builtin_amdgcn_mfma_f32_16x16x32_bf16(am[mi], bn[ni], acc[mi][ni], 0, 0, 0);
        }
        __syncthreads();
    }
}

// ---------------------------------------------------------------------------
// QKV projection: grid (64, 8, 3). A = xb [8192][1024]. B = W?T [1024 n][1024 k].
// z=0 -> Q[b,h,s,e] pre-scaled by QSCALE; z=1 -> K[b,h,s,e]; z=2 -> VT[(b*1024+n)][s]
// ---------------------------------------------------------------------------
__global__ __launch_bounds__(256, 3) void qkv_gemm128(const short* __restrict__ xb,
                                                      const short* __restrict__ WqT,
                                                      const short* __restrict__ WkT,
                                                      const short* __restrict__ WvT,
                                                      short* __restrict__ Q,
                                                      short* __restrict__ K,
                                                      short* __restrict__ VT) {
    __shared__ alignas(16) short lds[16384];  // 32 KB: staging A|B, reused as epilogue bounce
    short* ldsA = lds;
    short* ldsB = lds + 8192;
    int m0 = blockIdx.x * 128, n0 = blockIdx.y * 128, z = blockIdx.z;
    const short* Bm = (z == 0) ? WqT : (z == 1) ? WkT : WvT;
    int tid = threadIdx.x, w = tid >> 6, lane = tid & 63, quad = lane >> 4, lm = lane & 15;

    floatx4 acc[4][4];
#pragma unroll
    for (int mi = 0; mi < 4; ++mi)
#pragma unroll
        for (int ni = 0; ni < 4; ++ni) acc[mi][ni] = (floatx4)0.0f;

    gemm128_core(xb, Bm, ldsA, ldsB, m0, n0, acc, w, lane, quad, lm);

    int wm = (w >> 1) * 64, wn = (w & 1) * 64;
    int b = m0 >> 11;
    int sbase = m0 & 2047;

    if (z < 2) {
        short* O = (z == 0) ? Q : K;
        float scale = (z == 0) ? QSCALE : 1.0f;
        short* t = lds;  // 128 x 68
#pragma unroll
        for (int ph = 0; ph < 2; ++ph) {
            if (ph) __syncthreads();
            if ((w & 1) == ph) {
#pragma unroll
                for (int mi = 0; mi < 4; ++mi)
#pragma unroll
                    for (int ni = 0; ni < 4; ++ni)
#pragma unroll
                        for (int r = 0; r < 4; ++r)
                            t[(wm + mi * 16 + quad * 4 + r) * 68 + ni * 16 + lm] =
                                f2bf(acc[mi][ni][r] * scale);
            }
            __syncthreads();
            int h = (n0 + ph * 64) >> 6;
            size_t obase = ((size_t)(b * 16 + h) * 2048 + sbase) * 64;
#pragma unroll
            for (int i = 0; i < 4; ++i) {
                int c = tid + i * 256;
                int m = c >> 3, e8 = (c & 7) * 8;
                short8 v = *(const short8*)(t + m * 68 + e8);
                *(short8*)(O + obase + (size_t)m * 64 + e8) = v;
            }
        }
    } else {
        // transpose 128x128 tile through LDS (two 64-n halves) -> VT[b*1024+n][s]
        short* t = lds;  // 64 x 136
#pragma unroll
        for (int ph = 0; ph < 2; ++ph) {
            if (ph) __syncthreads();
            if ((w & 1) == ph) {
#pragma unroll
                for (int mi = 0; mi < 4; ++mi)
#pragma unroll
                    for (int ni = 0; ni < 4; ++ni) {
                        int nl = ni * 16 + lm;
#pragma unroll
                        for (int r = 0; r < 4; ++r) {
                            int ml = wm + mi * 16 + quad * 4 + r;
                            t[nl * 136 + ml] = f2bf(acc[mi][ni][r]);
                        }
                    }
            }
            __syncthreads();
#pragma unroll
            for (int i = 0; i < 4; ++i) {
                int c = tid + i * 256;
                int rowl = c >> 4, colc = (c & 15) * 8;
                short8 v = *(const short8*)(t + rowl * 136 + colc);
                size_t n = n0 + ph * 64 + rowl;
                *(short8*)(VT + ((size_t)b * 1024 + n) * 2048 + sbase + colc) = v;
            }
        }
    }
}

// ---------------------------------------------------------------------------
// Output projection: out[8192][1024] f32 = CC @ WoT^T + bo. grid (64, 8).
// ---------------------------------------------------------------------------
__global__ __launch_bounds__(256, 3) void outproj128(const short* __restrict__ CC,
                                                     const short* __restrict__ WoT,
                                                     const float* __restrict__ bo,
                                                     float* __restrict__ out) {
    __shared__ alignas(16) short lds[16384];
    short* ldsA = lds;
    short* ldsB = lds + 8192;
    int m0 = blockIdx.x * 128, n0 = blockIdx.y * 128;
    int tid = threadIdx.x, w = tid >> 6, lane = tid & 63, quad = lane >> 4, lm = lane & 15;

    floatx4 acc[4][4];
#pragma unroll
    for (int mi = 0; mi < 4; ++mi)
#pragma unroll
        for (int ni = 0; ni < 4; ++ni) acc[mi][ni] = (floatx4)0.0f;

    gemm128_core(CC, WoT, ldsA, ldsB, m0, n0, acc, w, lane, quad, lm);

    int wm = (w >> 1) * 64, wn = (w & 1) * 64;
#pragma unroll
    for (int mi = 0; mi < 4; ++mi)
#pragma unroll
        for (int ni = 0; ni < 4; ++ni) {
            int n = n0 + wn + ni * 16 + lm;
            float bb = bo[n];
#pragma unroll
            for (int r = 0; r < 4; ++r) {
                int m = m0 + wm + mi * 16 + quad * 4 + r;
                out[(size_t)m * 1024 + n] = acc[mi][ni][r] + bb;
            }
        }
}

// ---------------------------------------------------------------------------
// Causal flash attention v11: 32x32 MFMA + in-register P (T12).
// r8 cycle model: v9's LDS pipe ran at ~84% (40 b128 reads + 16 b64 writes
// per wave per k-tile) — the binding resource. v11 deletes the entire P
// LDS round-trip:
//  - QK^T via mfma_32x32x16: wave owns 32 q-rows; S^T col=lane&31 (q),
//    row=(r&3)+8*(r>>2)+4*(lane>>5) (t)  [guide-verified m74/m101 layout]
//  - P->PV A-frags built IN REGISTERS: per 16-t step, 4x v_cvt_pk_bf16_f32
//    + 2x v_permlane32_swap_b32 (T12; lane algebra verified: swap of
//    cvtpk(p[8s],p[8s+1]) with cvtpk(p[8s+4],p[8s+5]) yields A-frag dwords
//    0 and 2 for both lane-halves; the +2/+3,+6/+7 pair yields dwords 1,3)
//  - PV via mfma_32x32x16: O row=q (crow), col=e=eb*32+lane&31
// Per-wave per-tile LDS: 16 K-frag + 16 V-frag b128 reads (even 8-slot
// distribution -> conflict floor), ZERO P ops. Pt deleted: LDS 64 -> 32 KB.
// Staging, grid (64 bh, 8 pi) ps-paired, XCD mapping, setprio: unchanged v9.
// Regs: st 64 + acc 32 + qa 16 + transients ~= 150-190 < 256 cap -> no spill.
// ---------------------------------------------------------------------------
__global__ __launch_bounds__(256, 2) void attn_kernel(const short* __restrict__ Q,
                                                      const short* __restrict__ Kb,
                                                      const short* __restrict__ VT,
                                                      short* __restrict__ CC) {
    __shared__ alignas(16) short Kt[128 * 64];   // swizzled chunks
    __shared__ alignas(16) short Vt[64 * 128];   // swizzled chunks
    int bh = blockIdx.x;
    int pi = blockIdx.y;
    int b = bh >> 4, h = bh & 15;
    int tid = threadIdx.x;
    int w = tid >> 6, l = tid & 63;
    int hi = l >> 5, l31 = l & 31, l7 = l & 7;
    int rsub = l >> 3;              // K staging row-within-8
    int csw = ((l & 7) ^ rsub) * 8; // K staging swizzled chunk offset
    int vr4 = l >> 4;               // V staging row-within-4
    int vc = l & 15;

    const short* Qbh = Q + (size_t)bh * S_ * DH_;
    const short* Kbh = Kb + (size_t)bh * S_ * DH_;
    const short* Vbh = VT + (size_t)bh * 64 * S_;

    for (int ps = 0; ps < 2; ++ps) {
        int qt = ps ? (15 - pi) : pi;
        int q0 = qt * 128;
        int qrow = q0 + w * 32 + l31;   // the q-row this lane's S^T column owns

        // Q B-frags: col q = lane&31, k = ks*16 + hi*8 + j
        short8 qa[4];
        const short* Qrow = Qbh + (size_t)qrow * DH_;
#pragma unroll
        for (int ks = 0; ks < 4; ++ks)
            qa[ks] = *(const short8*)(Qrow + ks * 16 + hi * 8);

        floatx16 acc[2];
        acc[0] = (floatx16)0.0f;
        acc[1] = (floatx16)0.0f;
        float lsum = 0.0f;

        int nkt = qt + 1;
        for (int kt = 0; kt < nkt; ++kt) {
            int t0 = kt * 128;
            // stage Kt[128][64] (rows contiguous) and Vt[64][128] (rows stride S_)
            const short* Ktile = Kbh + (size_t)t0 * DH_;
#pragma unroll
            for (int i = 0; i < 4; ++i) {
                int r0 = w * 32 + i * 8;
                const short* ga = Ktile + (size_t)(r0 + rsub) * 64 + csw;
                __builtin_amdgcn_global_load_lds((const __attribute__((address_space(1))) void*)ga,
                                                 (__attribute__((address_space(3))) void*)(Kt + r0 * 64),
                                                 16, 0, 0);
            }
#pragma unroll
            for (int i = 0; i < 4; ++i) {
                int r0v = w * 16 + i * 4;
                int row = r0v + vr4;
                const short* gv = Vbh + (size_t)row * S_ + t0 + ((vc ^ (row & 7)) * 8);
                __builtin_amdgcn_global_load_lds((const __attribute__((address_space(1))) void*)gv,
                                                 (__attribute__((address_space(3))) void*)(Vt + r0v * 128),
                                                 16, 0, 0);
            }
            __syncthreads();

            // QK^T: S^T[t=128][q=128] ; wave covers its 32 q for all 128 t
            floatx16 st[4];
            __builtin_amdgcn_s_setprio(1);
#pragma unroll
            for (int tb = 0; tb < 4; ++tb) {
                floatx16 t = (floatx16)0.0f;
#pragma unroll
                for (int ks = 0; ks < 4; ++ks) {
                    // A=K frag: row t = tb*32 + lane&31, k = ks*16 + hi*8 + j
                    short8 kf = *(const short8*)(Kt + (tb * 32 + l31) * 64 +
                                                 (((ks * 2 + hi) ^ l7) << 3));
                    t = __builtin_amdgcn_mfma_f32_32x32x16_bf16(kf, qa[ks], t, 0, 0, 0);
                }
                st[tb] = t;
            }
            __builtin_amdgcn_s_setprio(0);

            if (kt == nkt - 1) {
#pragma unroll
                for (int tb = 0; tb < 4; ++tb)
#pragma unroll
                    for (int r = 0; r < 16; ++r) {
                        int t_ = t0 + tb * 32 + (r & 3) + 8 * (r >> 2) + 4 * hi;
                        if (t_ > qrow) st[tb][r] = -INFINITY;
                    }
            }

            // exp2 (scores pre-scaled into log2 domain) + row-sum (lane owns q)
#pragma unroll
            for (int tb = 0; tb < 4; ++tb)
#pragma unroll
                for (int r = 0; r < 16; r += 4) {
                    float p0 = exp2f(st[tb][r]);
                    float p1 = exp2f(st[tb][r + 1]);
                    float p2 = exp2f(st[tb][r + 2]);
                    float p3 = exp2f(st[tb][r + 3]);
                    st[tb][r] = p0; st[tb][r + 1] = p1;
                    st[tb][r + 2] = p2; st[tb][r + 3] = p3;
                    lsum += (p0 + p1) + (p2 + p3);
                }

            // PV: build P A-frags in registers (cvt_pk + permlane32_swap), no LDS
            __builtin_amdgcn_s_setprio(1);
#pragma unroll
            for (int tb = 0; tb < 4; ++tb)
#pragma unroll
                for (int sl = 0; sl < 2; ++sl) {
                    unsigned x0, y0, x1, y1;
                    asm("v_cvt_pk_bf16_f32 %0, %1, %2" : "=v"(x0)
                        : "v"(st[tb][sl * 8 + 0]), "v"(st[tb][sl * 8 + 1]));
                    asm("v_cvt_pk_bf16_f32 %0, %1, %2" : "=v"(y0)
                        : "v"(st[tb][sl * 8 + 4]), "v"(st[tb][sl * 8 + 5]));
                    asm("v_cvt_pk_bf16_f32 %0, %1, %2" : "=v"(x1)
                        : "v"(st[tb][sl * 8 + 2]), "v"(st[tb][sl * 8 + 3]));
                    asm("v_cvt_pk_bf16_f32 %0, %1, %2" : "=v"(y1)
                        : "v"(st[tb][sl * 8 + 6]), "v"(st[tb][sl * 8 + 7]));
                    // x' = [x_lo, y_lo] -> dword0/1 ; y' = [x_hi, y_hi] -> dword2/3
                    asm("v_permlane32_swap_b32 %0, %1" : "+v"(x0), "+v"(y0));
                    asm("v_permlane32_swap_b32 %0, %1" : "+v"(x1), "+v"(y1));
                    uintx4 pd;
                    pd[0] = x0; pd[1] = x1; pd[2] = y0; pd[3] = y1;
                    short8 pa = __builtin_bit_cast(short8, pd);
                    int s = tb * 2 + sl;
#pragma unroll
                    for (int eb = 0; eb < 2; ++eb) {
                        // B=V frag: col e = eb*32 + lane&31, k = t = s*16 + hi*8 + j
                        short8 v = *(const short8*)(Vt + (eb * 32 + l31) * 128 +
                                                    (((s * 2 + hi) ^ l7) << 3));
                        acc[eb] = __builtin_amdgcn_mfma_f32_32x32x16_bf16(pa, v, acc[eb], 0, 0, 0);
                    }
                }
            __builtin_amdgcn_s_setprio(0);
            __syncthreads();  // protects Kt/Vt restage next iteration
        }

        // each q's full row-sum lives split across lane and lane^32
        float lt = lsum + __shfl_xor(lsum, 32);
        float invl = 1.0f / lt;

        // O layout: row q_local = (r&3)+8*(r>>2)+4*hi, col e = eb*32 + lane&31
#pragma unroll
        for (int r = 0; r < 16; ++r) {
            int q_local = (r & 3) + 8 * (r >> 2) + 4 * hi;
            float iv = __shfl(invl, q_local);  // invl for q=q_local lives at lane q_local
            int row = q0 + w * 32 + q_local;
            short* OC = CC + ((size_t)b * S_ + row) * D_ + h * DH_;
#pragma unroll
            for (int eb = 0; eb < 2; ++eb)
                OC[eb * 32 + l31] = f2bf(acc[eb][r] * iv);
        }
    }
}

extern "C" void kernel_launch(void* const* d_in, const int* in_sizes, int n_in,
                              void* d_out, int out_size, void* d_ws, size_t ws_size,
                              hipStream_t stream) {
    const float* x  = (const float*)d_in[0];
    const float* Wq = (const float*)d_in[1];
    const float* Wk = (const float*)d_in[2];
    const float* Wv = (const float*)d_in[3];
    const float* Wo = (const float*)d_in[4];
    const float* bo = (const float*)d_in[5];
    float* out = (float*)d_out;
    short* ws = (short*)d_ws;

    const size_t WSZ = (size_t)H_ * D_ * DH_;        // 1,048,576
    const size_t QSZ = (size_t)B_ * H_ * S_ * DH_;   // 8,388,608
    short* WqT = ws;
    short* WkT = WqT + WSZ;
    short* WvT = WkT + WSZ;
    short* WoT = WvT + WSZ;
    short* xb  = WoT + (size_t)D_ * D_;
    short* Qb  = xb + (size_t)B_ * S_ * D_;
    short* Kb  = Qb + QSZ;
    short* VTb = Kb + QSZ;
    short* CCb = VTb + QSZ;

    convert_x<<<(B_ * S_ * D_ / 8 + 255) / 256, 256, 0, stream>>>(x, xb, B_ * S_ * D_ / 8);
    prep_weights<<<dim3(16, 16, 4), 256, 0, stream>>>(Wq, Wk, Wv, Wo, WqT, WkT, WvT, WoT);
    qkv_gemm128<<<dim3(64, 8, 3), 256, 0, stream>>>(xb, WqT, WkT, WvT, Qb, Kb, VTb);
    attn_kernel<<<dim3(64, 8), 256, 0, stream>>>(Qb, Kb, VTb, CCb);
    outproj128<<<dim3(64, 8), 256, 0, stream>>>(CCb, WoT, bo, out);
}